// Round 11
// baseline (87.864 us; speedup 1.0000x reference)
//
#include <hip/hip_runtime.h>
#include <math.h>
#include <type_traits>

namespace {
constexpr int B = 4, S = 2048, E = 512, D = 64, H = 8;
constexpr int KD = 512;

typedef short bf8 __attribute__((ext_vector_type(8)));
typedef short bf4 __attribute__((ext_vector_type(4)));
typedef float f4 __attribute__((ext_vector_type(4)));

__device__ __forceinline__ short f2bf(float f) {
  union { float f; unsigned u; } v; v.f = f;
  const unsigned r = v.u + 0x7fffu + ((v.u >> 16) & 1u);  // RNE
  return (short)(r >> 16);
}

__device__ __forceinline__ unsigned cvt_pk_bf16(float a, float b) {
  unsigned r;
  asm("v_cvt_pk_bf16_f32 %0, %1, %2" : "=v"(r) : "v"(a), "v"(b));
  return r;  // lo16 = bf16(a), hi16 = bf16(b)
}

__device__ __forceinline__ void gload16(const void* g, void* l) {
  __builtin_amdgcn_global_load_lds(
      (const __attribute__((address_space(1))) unsigned int*)g,
      (__attribute__((address_space(3))) unsigned int*)l, 16, 0, 0);
}

// ---------------------------------------------------------------------------
// fused prep: [0,2048) xb convert; [2048,2240) WcatT; [2240,2304) W2T
// ---------------------------------------------------------------------------
__global__ __launch_bounds__(256) void prep_kernel(
    const float* __restrict__ x, const float* __restrict__ Wq,
    const float* __restrict__ Wk, const float* __restrict__ Wvd,
    const float* __restrict__ Wvu, const float* __restrict__ Wo,
    short* __restrict__ xb, short* __restrict__ WcatT,
    short* __restrict__ W2T) {
  __shared__ float T[64][65];
  const int bid = blockIdx.x;
  const int tid = threadIdx.x;
  if (bid < 2048) {
    const size_t i = ((size_t)bid * 256 + tid) * 8;
    const float4 v0 = *(const float4*)(x + i);
    const float4 v1 = *(const float4*)(x + i + 4);
    bf8 o;
    o[0] = f2bf(v0.x); o[1] = f2bf(v0.y); o[2] = f2bf(v0.z); o[3] = f2bf(v0.w);
    o[4] = f2bf(v1.x); o[5] = f2bf(v1.y); o[6] = f2bf(v1.z); o[7] = f2bf(v1.w);
    *(bf8*)(xb + i) = o;
  } else if (bid < 2240) {
    const int r = bid - 2048;
    const int cb = r >> 3, e0 = (r & 7) * 64;
    const int w = cb >> 3, h = cb & 7;
    const float* Wsel = (w == 0) ? Wq : (w == 1) ? Wk : Wvd;
    const float* Wp = Wsel + (size_t)h * E * D;
#pragma unroll
    for (int i = 0; i < 4; ++i) {
      const int f = tid + i * 256;
      const int rr = f >> 4, c4 = f & 15;
      const float4 v = *(const float4*)(Wp + (size_t)(e0 + rr) * D + c4 * 4);
      T[rr][c4 * 4 + 0] = v.x; T[rr][c4 * 4 + 1] = v.y;
      T[rr][c4 * 4 + 2] = v.z; T[rr][c4 * 4 + 3] = v.w;
    }
    __syncthreads();
#pragma unroll
    for (int i = 0; i < 4; ++i) {
      const int f = tid + i * 256;
      const int dr = f >> 4, e4 = f & 15;
      bf4 o;
#pragma unroll
      for (int j = 0; j < 4; ++j) o[j] = f2bf(T[e4 * 4 + j][dr]);
      *(bf4*)(WcatT + (size_t)(cb * 64 + dr) * KD + e0 + e4 * 4) = o;
    }
  } else {
    const int r = bid - 2240;
    const int h = r >> 3, e0 = (r & 7) * 64;
    const float wo = Wo[h];
#pragma unroll
    for (int i = 0; i < 4; ++i) {
      const int f = tid + i * 256;
      const int rr = f >> 4, c4 = f & 15;
      const float4 v = *(const float4*)(Wvu + ((size_t)h * D + rr) * E + e0 + c4 * 4);
      T[rr][c4 * 4 + 0] = v.x * wo; T[rr][c4 * 4 + 1] = v.y * wo;
      T[rr][c4 * 4 + 2] = v.z * wo; T[rr][c4 * 4 + 3] = v.w * wo;
    }
    __syncthreads();
#pragma unroll
    for (int i = 0; i < 4; ++i) {
      const int f = tid + i * 256;
      const int er = f >> 4, d4 = f & 15;
      bf4 o;
#pragma unroll
      for (int j = 0; j < 4; ++j) o[j] = f2bf(T[d4 * 4 + j][er]);
      *(bf4*)(W2T + (size_t)(e0 + er) * KD + h * 64 + d4 * 4) = o;
    }
  }
}

// ---------------------------------------------------------------------------
// bf16 MFMA GEMM.  MODE 0: proj -> Qb/Kb (row-major [bh][s][d]) and V^T
// (Vt[bh][d][s], bf4 stores; 8B halves of each 16B granule swapped for rows
// with (d>>3)&1 -- bank-spread permutation consumed by attn).
// MODE 1: out epilogue (fp32 row-major).
// ---------------------------------------------------------------------------
template <int MODE>
__global__ __launch_bounds__(256) void gemm_kernel(
    const short* __restrict__ A, const short* __restrict__ Bt,
    short* __restrict__ Qb, short* __restrict__ Kb, short* __restrict__ Vtg,
    float* __restrict__ Of) {
  const int row0 = blockIdx.x * 128;
  const int ct = blockIdx.y;
  const int tid = threadIdx.x;
  const int w = tid >> 6, l = tid & 63;
  const int wm = w >> 1, wn = w & 1;
  const int lr = l & 15, hi = l >> 4;

  __shared__ short As[128 * 64];
  __shared__ short Bs[128 * 64];

  const short* Ag = A + (size_t)row0 * KD;
  const short* Bg = Bt + (size_t)ct * 128 * KD;

  f4 acc[4][4] = {};
  for (int k0 = 0; k0 < KD; k0 += 64) {
    __syncthreads();
#pragma unroll
    for (int i = 0; i < 4; ++i) {
      const int f = i * 256 + tid;
      const int r = f >> 3, g = f & 7;
      gload16(Ag + (size_t)r * KD + k0 + ((g ^ (r & 7)) << 3), &As[f * 8]);
    }
#pragma unroll
    for (int i = 0; i < 4; ++i) {
      const int f = i * 256 + tid;
      const int r = f >> 3, g = f & 7;
      gload16(Bg + (size_t)r * KD + k0 + ((g ^ (r & 7)) << 3), &Bs[f * 8]);
    }
    __syncthreads();

    bf8 af[4][2], bfv[4][2];
#pragma unroll
    for (int t = 0; t < 4; ++t) {
#pragma unroll
      for (int kh = 0; kh < 2; ++kh) {
        const int ar = wm * 64 + t * 16 + lr;
        af[t][kh] = *(const bf8*)&As[ar * 64 + (((kh * 4 + hi) ^ (ar & 7)) << 3)];
        const int br = wn * 64 + t * 16 + lr;
        bfv[t][kh] = *(const bf8*)&Bs[br * 64 + (((kh * 4 + hi) ^ (br & 7)) << 3)];
      }
    }
#pragma unroll
    for (int mt = 0; mt < 4; ++mt)
#pragma unroll
      for (int nt = 0; nt < 4; ++nt) {
        acc[mt][nt] =
            __builtin_amdgcn_mfma_f32_16x16x32_bf16(af[mt][0], bfv[nt][0], acc[mt][nt], 0, 0, 0);
        acc[mt][nt] =
            __builtin_amdgcn_mfma_f32_16x16x32_bf16(af[mt][1], bfv[nt][1], acc[mt][nt], 0, 0, 0);
      }
  }

  if constexpr (MODE == 0) {
#pragma unroll
    for (int nt = 0; nt < 4; ++nt) {
      const int gc = ct * 128 + wn * 64 + nt * 16 + lr;
      const int cb = gc >> 6, d = gc & 63;
      const int h = cb & 7;
      if (cb < 16) {
        short* Out = (cb < 8) ? Qb : Kb;
#pragma unroll
        for (int mt = 0; mt < 4; ++mt)
#pragma unroll
          for (int reg = 0; reg < 4; ++reg) {
            const int grow = row0 + wm * 64 + mt * 16 + hi * 4 + reg;
            const int b = grow >> 11, s = grow & (S - 1);
            Out[(((size_t)(b * H + h) * S + s) << 6) + d] = f2bf(acc[mt][nt][reg]);
          }
      } else {
        // V^T: Vt[bh][d][s]; swap 8B halves within 16B granules on rows
        // with (d>>3)&1 to spread LDS banks for attn's b64 reads.
        const int hswap = ((d >> 3) & 1) << 2;
#pragma unroll
        for (int mt = 0; mt < 4; ++mt) {
          const int grow0 = row0 + wm * 64 + mt * 16 + hi * 4;
          const int b = grow0 >> 11, s0 = (grow0 & (S - 1)) ^ hswap;
          bf4 o;
#pragma unroll
          for (int reg = 0; reg < 4; ++reg) o[reg] = f2bf(acc[mt][nt][reg]);
          *(bf4*)(Vtg + (((size_t)(b * H + h) * D + d) << 11) + s0) = o;
        }
      }
    }
  } else {
#pragma unroll
    for (int mt = 0; mt < 4; ++mt)
#pragma unroll
      for (int reg = 0; reg < 4; ++reg) {
        const int grow = row0 + wm * 64 + mt * 16 + hi * 4 + reg;
        float* orow = Of + (size_t)grow * 512 + ct * 128 + wn * 64;
#pragma unroll
        for (int nt = 0; nt < 4; ++nt) orow[nt * 16 + lr] = acc[mt][nt][reg];
      }
  }
}

// ---------------------------------------------------------------------------
// attn v8: balanced triangle pairing + TRIPLE-buffer single-barrier pipeline.
// Hazard proof: prefetch at step s targets buf[(s+1)%3], last read during
// compute(s-2); all waves passed barrier_{s-1} => finished compute(s-2).
// Swapped QK^T, fixed-max softmax (exp2, M=12), in-register P (K=16 PV MFMA),
// counted vmcnt(4), precomputed lane-constant LDS offsets.
// ---------------------------------------------------------------------------
__global__ __launch_bounds__(256) void attn_kernel(
    const short* __restrict__ Qb, const short* __restrict__ Kb,
    const short* __restrict__ Vt, short* __restrict__ PVb) {
  const int bh = blockIdx.x;
  const int j = blockIdx.y;            // pair index 0..15
  const int qtA = j, qtB = 31 - j;
  const int nA = j + 1;                // steps in phase A (33 total)
  const int b = bh >> 3, h = bh & 7;
  const int tid = threadIdx.x;
  const int w = tid >> 6, l = tid & 63;
  const int lr = l & 15, hi = l >> 4;

  __shared__ short Ks[3][64 * 64];
  __shared__ short Vs[3][64 * 64];

  // Q fragments (B operand of swapped QK^T) for both phases
  const short* QgA = Qb + ((size_t)bh * S + qtA * 64 + w * 16 + lr) * D;
  const short* QgB = Qb + ((size_t)bh * S + qtB * 64 + w * 16 + lr) * D;
  const bf8 qA0 = *(const bf8*)(QgA + hi * 8);
  const bf8 qA1 = *(const bf8*)(QgA + 32 + hi * 8);
  const bf8 qB0 = *(const bf8*)(QgB + hi * 8);
  const bf8 qB1 = *(const bf8*)(QgB + 32 + hi * 8);

  const short* Kg = Kb + (size_t)bh * S * D;   // [t][64]
  const short* Vg = Vt + (size_t)bh * D * S;   // [e][S] (half-swapped rows)

  // staging lane addresses (fixed; tile offset added per step)
  const int sr = tid >> 3, sg = tid & 7;
  const int sswz = (sg ^ (sr & 7)) << 3;
  const int sr2 = sr + 32, sswz2 = (sg ^ (sr2 & 7)) << 3;
  const short* kg0 = Kg + (size_t)sr * D + sswz;
  const short* kg1 = Kg + (size_t)sr2 * D + sswz2;
  const short* vg0 = Vg + (size_t)sr * S + sswz;
  const short* vg1 = Vg + (size_t)sr2 * S + sswz2;

  // precomputed lane-constant LDS byte offsets
  const int e7 = lr & 7;
  const int kla0 = lr * 128 + ((hi ^ e7) << 4);
  const int kla1 = kla0 ^ 64;
  const int x7 = (hi >> 1) ^ e7;
  const int swaph = ((hi & 1) ^ ((lr >> 3) & 1)) << 3;
  int vla[4];
#pragma unroll
  for (int np = 0; np < 4; ++np)
    vla[np] = lr * 128 + (((2 * np) ^ x7) << 4) + swaph;

  float lsum4[4] = {};
  f4 accO[4] = {};

  constexpr float LOG2E = 1.44269504088896340736f;
  constexpr float C1 = 0.125f * LOG2E;
  constexpr float C0 = -12.0f * LOG2E;

  auto step = [&](int buf, bf8 q0, bf8 q1, auto diag_c) {
    constexpr bool DIAG = decltype(diag_c)::value;
    const char* Klb = (const char*)Ks[buf];
    const char* Vlb = (const char*)Vs[buf];
    // QK^T swapped: A = K (rows t), B = Q (cols q) -> D[t][q]
    f4 accS[4] = {};
    __builtin_amdgcn_s_setprio(1);
#pragma unroll
    for (int n = 0; n < 4; ++n) {
      const bf8 k0 = *(const bf8*)(Klb + kla0 + n * 2048);
      const bf8 k1 = *(const bf8*)(Klb + kla1 + n * 2048);
      accS[n] = __builtin_amdgcn_mfma_f32_16x16x32_bf16(k0, q0, accS[n], 0, 0, 0);
      accS[n] = __builtin_amdgcn_mfma_f32_16x16x32_bf16(k1, q1, accS[n], 0, 0, 0);
    }
    __builtin_amdgcn_s_setprio(0);

    // p = exp2(sv*C1 + C0) (fixed-max softmax); diag applies causal mask
    bf4 pa[4];
#pragma unroll
    for (int n = 0; n < 4; ++n) {
      float p[4];
#pragma unroll
      for (int reg = 0; reg < 4; ++reg) {
        float pv = exp2f(fmaf(accS[n][reg], C1, C0));
        if constexpr (DIAG) {
          const bool ok = (n * 16 + hi * 4 + reg) <= (w * 16 + lr);
          pv = ok ? pv : 0.f;
        }
        p[reg] = pv;
        lsum4[reg] += pv;
      }
      union { int2 i; bf4 v; } u;
      u.i.x = (int)cvt_pk_bf16(p[0], p[1]);
      u.i.y = (int)cvt_pk_bf16(p[2], p[3]);
      pa[n] = u.v;
    }

    // PV: O[q][e] += P16[np] @ V16[np], A from registers, B b64 from LDS
    __builtin_amdgcn_s_setprio(1);
#pragma unroll
    for (int np = 0; np < 4; ++np) {
#pragma unroll
      for (int ne = 0; ne < 4; ++ne) {
        const bf4 vf = *(const bf4*)(Vlb + vla[np] + ne * 2048);
        accO[ne] = __builtin_amdgcn_mfma_f32_16x16x16bf16_1k(pa[np], vf, accO[ne], 0, 0, 0);
      }
    }
    __builtin_amdgcn_s_setprio(0);
  };

  auto epi = [&](int qt) {
    float lv = (lsum4[0] + lsum4[1]) + (lsum4[2] + lsum4[3]);
    lv += __shfl_xor(lv, 16);
    lv += __shfl_xor(lv, 32);   // all lanes: full denominator for q = lr
#pragma unroll
    for (int reg = 0; reg < 4; ++reg) {
      const float lq = __shfl(lv, hi * 4 + reg);
      const float inv = 1.f / lq;
      const int s = qt * 64 + w * 16 + hi * 4 + reg;
      short* op = PVb + (size_t)(b * S + s) * (H * D) + h * D;
#pragma unroll
      for (int n = 0; n < 4; ++n) op[n * 16 + lr] = f2bf(accO[n][reg] * inv);
    }
  };

  // prologue: stage tile 0 (phase A kt=0) into buf 0
  gload16(kg0, &Ks[0][tid * 8]);
  gload16(kg1, &Ks[0][(256 + tid) * 8]);
  gload16(vg0, &Vs[0][tid * 8]);
  gload16(vg1, &Vs[0][(256 + tid) * 8]);

  int buf = 0, nbuf = 1;
  for (int s = 0; s < 33; ++s) {
    if (s < 32) {
      const int ktn = (s + 1 < nA) ? s + 1 : s + 1 - nA;  // next tile index
      const size_t ko = (size_t)ktn << 12;  // shorts: ktn*64 rows * 64
      const size_t vo = (size_t)ktn << 6;   // shorts: ktn*64 cols
      gload16(kg0 + ko, &Ks[nbuf][tid * 8]);
      gload16(kg1 + ko, &Ks[nbuf][(256 + tid) * 8]);
      gload16(vg0 + vo, &Vs[nbuf][tid * 8]);
      gload16(vg1 + vo, &Vs[nbuf][(256 + tid) * 8]);
      asm volatile("s_waitcnt vmcnt(4)" ::: "memory");  // current tile's loads done
    } else {
      asm volatile("s_waitcnt vmcnt(0)" ::: "memory");
    }
    __builtin_amdgcn_sched_barrier(0);
    __builtin_amdgcn_s_barrier();     // all waves' current-tile loads visible
    __builtin_amdgcn_sched_barrier(0);

    if (s < nA) {
      if (s == nA - 1) step(buf, qA0, qA1, std::true_type{});
      else             step(buf, qA0, qA1, std::false_type{});
    } else {
      if (s == 32)     step(buf, qB0, qB1, std::true_type{});
      else             step(buf, qB0, qB1, std::false_type{});
    }

    if (s == nA - 1) {  // phase A done: write its output, reset state
      epi(qtA);
#pragma unroll
      for (int n = 0; n < 4; ++n) accO[n] = f4{0.f, 0.f, 0.f, 0.f};
      lsum4[0] = lsum4[1] = lsum4[2] = lsum4[3] = 0.f;
    }
    buf = nbuf;
    nbuf = (nbuf == 2) ? 0 : nbuf + 1;
  }
  epi(qtB);
}

}  // namespace

extern "C" void kernel_launch(void* const* d_in, const int* in_sizes, int n_in,
                              void* d_out, int out_size, void* d_ws, size_t ws_size,
                              hipStream_t stream) {
  const float* x   = (const float*)d_in[0];
  const float* Wq  = (const float*)d_in[1];
  const float* Wk  = (const float*)d_in[2];
  const float* Wvd = (const float*)d_in[3];
  const float* Wvu = (const float*)d_in[4];
  const float* Wo  = (const float*)d_in[5];
  float* out = (float*)d_out;

  const size_t nqk = (size_t)B * H * S * D;  // 4.19M
  short* xb    = (short*)d_ws;
  short* Qb    = xb + nqk;
  short* Kb    = Qb + nqk;
  short* Vtg   = Kb + nqk;
  short* PVb   = Vtg + nqk;
  short* WcatT = PVb + nqk;            // [1536][512]
  short* W2T   = WcatT + 1536 * KD;    // [512][512]

  prep_kernel<<<dim3(2304), 256, 0, stream>>>(x, Wq, Wk, Wvd, Wvu, Wo,
                                              xb, WcatT, W2T);
  gemm_kernel<0><<<dim3(64, 12), 256, 0, stream>>>(xb, WcatT, Qb, Kb, Vtg, nullptr);
  attn_kernel<<<dim3(B * H, 16), 256, 0, stream>>>(Qb, Kb, Vtg, PVb);
  gemm_kernel<1><<<dim3(64, 4), 256, 0, stream>>>(PVb, W2T, nullptr, nullptr, nullptr, out);
}

// Round 12
// 82.983 us; speedup vs baseline: 1.0588x; 1.0588x over previous
//
#include <hip/hip_runtime.h>
#include <math.h>
#include <type_traits>

namespace {
constexpr int B = 4, S = 2048, E = 512, D = 64, H = 8;
constexpr int KD = 512;

typedef short bf8 __attribute__((ext_vector_type(8)));
typedef short bf4 __attribute__((ext_vector_type(4)));
typedef float f4 __attribute__((ext_vector_type(4)));

__device__ __forceinline__ short f2bf(float f) {
  union { float f; unsigned u; } v; v.f = f;
  const unsigned r = v.u + 0x7fffu + ((v.u >> 16) & 1u);  // RNE
  return (short)(r >> 16);
}

__device__ __forceinline__ unsigned cvt_pk_bf16(float a, float b) {
  unsigned r;
  asm("v_cvt_pk_bf16_f32 %0, %1, %2" : "=v"(r) : "v"(a), "v"(b));
  return r;  // lo16 = bf16(a), hi16 = bf16(b)
}

__device__ __forceinline__ void gload16(const void* g, void* l) {
  __builtin_amdgcn_global_load_lds(
      (const __attribute__((address_space(1))) unsigned int*)g,
      (__attribute__((address_space(3))) unsigned int*)l, 16, 0, 0);
}

// ---------------------------------------------------------------------------
// fused prep: [0,2048) xb convert; [2048,2240) WcatT; [2240,2304) W2T
// ---------------------------------------------------------------------------
__global__ __launch_bounds__(256) void prep_kernel(
    const float* __restrict__ x, const float* __restrict__ Wq,
    const float* __restrict__ Wk, const float* __restrict__ Wvd,
    const float* __restrict__ Wvu, const float* __restrict__ Wo,
    short* __restrict__ xb, short* __restrict__ WcatT,
    short* __restrict__ W2T) {
  __shared__ float T[64][65];
  const int bid = blockIdx.x;
  const int tid = threadIdx.x;
  if (bid < 2048) {
    const size_t i = ((size_t)bid * 256 + tid) * 8;
    const float4 v0 = *(const float4*)(x + i);
    const float4 v1 = *(const float4*)(x + i + 4);
    bf8 o;
    o[0] = f2bf(v0.x); o[1] = f2bf(v0.y); o[2] = f2bf(v0.z); o[3] = f2bf(v0.w);
    o[4] = f2bf(v1.x); o[5] = f2bf(v1.y); o[6] = f2bf(v1.z); o[7] = f2bf(v1.w);
    *(bf8*)(xb + i) = o;
  } else if (bid < 2240) {
    const int r = bid - 2048;
    const int cb = r >> 3, e0 = (r & 7) * 64;
    const int w = cb >> 3, h = cb & 7;
    const float* Wsel = (w == 0) ? Wq : (w == 1) ? Wk : Wvd;
    const float* Wp = Wsel + (size_t)h * E * D;
#pragma unroll
    for (int i = 0; i < 4; ++i) {
      const int f = tid + i * 256;
      const int rr = f >> 4, c4 = f & 15;
      const float4 v = *(const float4*)(Wp + (size_t)(e0 + rr) * D + c4 * 4);
      T[rr][c4 * 4 + 0] = v.x; T[rr][c4 * 4 + 1] = v.y;
      T[rr][c4 * 4 + 2] = v.z; T[rr][c4 * 4 + 3] = v.w;
    }
    __syncthreads();
#pragma unroll
    for (int i = 0; i < 4; ++i) {
      const int f = tid + i * 256;
      const int dr = f >> 4, e4 = f & 15;
      bf4 o;
#pragma unroll
      for (int j = 0; j < 4; ++j) o[j] = f2bf(T[e4 * 4 + j][dr]);
      *(bf4*)(WcatT + (size_t)(cb * 64 + dr) * KD + e0 + e4 * 4) = o;
    }
  } else {
    const int r = bid - 2240;
    const int h = r >> 3, e0 = (r & 7) * 64;
    const float wo = Wo[h];
#pragma unroll
    for (int i = 0; i < 4; ++i) {
      const int f = tid + i * 256;
      const int rr = f >> 4, c4 = f & 15;
      const float4 v = *(const float4*)(Wvu + ((size_t)h * D + rr) * E + e0 + c4 * 4);
      T[rr][c4 * 4 + 0] = v.x * wo; T[rr][c4 * 4 + 1] = v.y * wo;
      T[rr][c4 * 4 + 2] = v.z * wo; T[rr][c4 * 4 + 3] = v.w * wo;
    }
    __syncthreads();
#pragma unroll
    for (int i = 0; i < 4; ++i) {
      const int f = tid + i * 256;
      const int er = f >> 4, d4 = f & 15;
      bf4 o;
#pragma unroll
      for (int j = 0; j < 4; ++j) o[j] = f2bf(T[d4 * 4 + j][er]);
      *(bf4*)(W2T + (size_t)(e0 + er) * KD + h * 64 + d4 * 4) = o;
    }
  }
}

// ---------------------------------------------------------------------------
// bf16 MFMA GEMM.  MODE 0: proj -> Qb/Kb (row-major [bh][s][d]) and V^T
// (Vt[bh][d][s], bf4 stores; 8B halves of each 16B granule swapped for rows
// with (d>>3)&1 -- bank-spread permutation consumed by attn).
// MODE 1: out epilogue (fp32 row-major).
// ---------------------------------------------------------------------------
template <int MODE>
__global__ __launch_bounds__(256) void gemm_kernel(
    const short* __restrict__ A, const short* __restrict__ Bt,
    short* __restrict__ Qb, short* __restrict__ Kb, short* __restrict__ Vtg,
    float* __restrict__ Of) {
  const int row0 = blockIdx.x * 128;
  const int ct = blockIdx.y;
  const int tid = threadIdx.x;
  const int w = tid >> 6, l = tid & 63;
  const int wm = w >> 1, wn = w & 1;
  const int lr = l & 15, hi = l >> 4;

  __shared__ short As[128 * 64];
  __shared__ short Bs[128 * 64];

  const short* Ag = A + (size_t)row0 * KD;
  const short* Bg = Bt + (size_t)ct * 128 * KD;

  f4 acc[4][4] = {};
  for (int k0 = 0; k0 < KD; k0 += 64) {
    __syncthreads();
#pragma unroll
    for (int i = 0; i < 4; ++i) {
      const int f = i * 256 + tid;
      const int r = f >> 3, g = f & 7;
      gload16(Ag + (size_t)r * KD + k0 + ((g ^ (r & 7)) << 3), &As[f * 8]);
    }
#pragma unroll
    for (int i = 0; i < 4; ++i) {
      const int f = i * 256 + tid;
      const int r = f >> 3, g = f & 7;
      gload16(Bg + (size_t)r * KD + k0 + ((g ^ (r & 7)) << 3), &Bs[f * 8]);
    }
    __syncthreads();

    bf8 af[4][2], bfv[4][2];
#pragma unroll
    for (int t = 0; t < 4; ++t) {
#pragma unroll
      for (int kh = 0; kh < 2; ++kh) {
        const int ar = wm * 64 + t * 16 + lr;
        af[t][kh] = *(const bf8*)&As[ar * 64 + (((kh * 4 + hi) ^ (ar & 7)) << 3)];
        const int br = wn * 64 + t * 16 + lr;
        bfv[t][kh] = *(const bf8*)&Bs[br * 64 + (((kh * 4 + hi) ^ (br & 7)) << 3)];
      }
    }
#pragma unroll
    for (int mt = 0; mt < 4; ++mt)
#pragma unroll
      for (int nt = 0; nt < 4; ++nt) {
        acc[mt][nt] =
            __builtin_amdgcn_mfma_f32_16x16x32_bf16(af[mt][0], bfv[nt][0], acc[mt][nt], 0, 0, 0);
        acc[mt][nt] =
            __builtin_amdgcn_mfma_f32_16x16x32_bf16(af[mt][1], bfv[nt][1], acc[mt][nt], 0, 0, 0);
      }
  }

  if constexpr (MODE == 0) {
#pragma unroll
    for (int nt = 0; nt < 4; ++nt) {
      const int gc = ct * 128 + wn * 64 + nt * 16 + lr;
      const int cb = gc >> 6, d = gc & 63;
      const int h = cb & 7;
      if (cb < 16) {
        short* Out = (cb < 8) ? Qb : Kb;
#pragma unroll
        for (int mt = 0; mt < 4; ++mt)
#pragma unroll
          for (int reg = 0; reg < 4; ++reg) {
            const int grow = row0 + wm * 64 + mt * 16 + hi * 4 + reg;
            const int b = grow >> 11, s = grow & (S - 1);
            Out[(((size_t)(b * H + h) * S + s) << 6) + d] = f2bf(acc[mt][nt][reg]);
          }
      } else {
        // V^T: Vt[bh][d][s]; swap 8B halves within 16B granules on rows
        // with (d>>3)&1 to spread LDS banks for attn's b64 reads.
        const int hswap = ((d >> 3) & 1) << 2;
#pragma unroll
        for (int mt = 0; mt < 4; ++mt) {
          const int grow0 = row0 + wm * 64 + mt * 16 + hi * 4;
          const int b = grow0 >> 11, s0 = (grow0 & (S - 1)) ^ hswap;
          bf4 o;
#pragma unroll
          for (int reg = 0; reg < 4; ++reg) o[reg] = f2bf(acc[mt][nt][reg]);
          *(bf4*)(Vtg + (((size_t)(b * H + h) * D + d) << 11) + s0) = o;
        }
      }
    }
  } else {
#pragma unroll
    for (int mt = 0; mt < 4; ++mt)
#pragma unroll
      for (int reg = 0; reg < 4; ++reg) {
        const int grow = row0 + wm * 64 + mt * 16 + hi * 4 + reg;
        float* orow = Of + (size_t)grow * 512 + ct * 128 + wn * 64;
#pragma unroll
        for (int nt = 0; nt < 4; ++nt) orow[nt * 16 + lr] = acc[mt][nt][reg];
      }
  }
}

// ---------------------------------------------------------------------------
// attn v9: r10 proven core (swapped QK^T, fixed-max __expf softmax, in-reg P,
// K=16 PV MFMA, balanced pairing) + TWO chunks per barrier pair.
// Quad-buffered LDS, prefetch 2 chunks ahead, vmcnt(8/4/0).
// Hazard: chunk c uses buf c&3; prefetch of c+2/c+3 issued only after the
// barrier confirming super-step s-1 (which read those bufs) is complete.
// ---------------------------------------------------------------------------
__global__ __launch_bounds__(256) void attn_kernel(
    const short* __restrict__ Qb, const short* __restrict__ Kb,
    const short* __restrict__ Vt, short* __restrict__ PVb) {
  const int bh = blockIdx.x;
  const int j = blockIdx.y;            // pair index 0..15
  const int qtA = j, qtB = 31 - j;
  const int nA = j + 1;                // chunks in phase A (33 total/block)
  const int b = bh >> 3, h = bh & 7;
  const int tid = threadIdx.x;
  const int w = tid >> 6, l = tid & 63;
  const int lr = l & 15, hi = l >> 4;

  __shared__ short Ks[4][64 * 64];
  __shared__ short Vs[4][64 * 64];

  // Q fragments (B operand of swapped QK^T) for both phases
  const short* QgA = Qb + ((size_t)bh * S + qtA * 64 + w * 16 + lr) * D;
  const short* QgB = Qb + ((size_t)bh * S + qtB * 64 + w * 16 + lr) * D;
  const bf8 qA0 = *(const bf8*)(QgA + hi * 8);
  const bf8 qA1 = *(const bf8*)(QgA + 32 + hi * 8);
  const bf8 qB0 = *(const bf8*)(QgB + hi * 8);
  const bf8 qB1 = *(const bf8*)(QgB + 32 + hi * 8);

  const short* Kg = Kb + (size_t)bh * S * D;   // [t][64]
  const short* Vg = Vt + (size_t)bh * D * S;   // [e][S] (half-swapped rows)

  // staging lane addresses (fixed; tile offset added per chunk)
  const int sr = tid >> 3, sg = tid & 7;
  const int sswz = (sg ^ (sr & 7)) << 3;
  const int sr2 = sr + 32, sswz2 = (sg ^ (sr2 & 7)) << 3;
  const short* kg0 = Kg + (size_t)sr * D + sswz;
  const short* kg1 = Kg + (size_t)sr2 * D + sswz2;
  const short* vg0 = Vg + (size_t)sr * S + sswz;
  const short* vg1 = Vg + (size_t)sr2 * S + sswz2;

  // precomputed lane-constant LDS byte offsets
  const int e7 = lr & 7;
  const int kla0 = lr * 128 + ((hi ^ e7) << 4);
  const int kla1 = kla0 ^ 64;
  const int x7 = (hi >> 1) ^ e7;
  const int swaph = ((hi & 1) ^ ((lr >> 3) & 1)) << 3;
  int vla[4];
#pragma unroll
  for (int np = 0; np < 4; ++np)
    vla[np] = lr * 128 + (((2 * np) ^ x7) << 4) + swaph;

  float lsum4[4] = {};
  f4 accO[4] = {};

  auto step = [&](int buf, bf8 q0, bf8 q1, auto diag_c) {
    constexpr bool DIAG = decltype(diag_c)::value;
    const char* Klb = (const char*)Ks[buf];
    const char* Vlb = (const char*)Vs[buf];
    // QK^T swapped: A = K (rows t), B = Q (cols q) -> D[t][q]
    f4 accS[4] = {};
    __builtin_amdgcn_s_setprio(1);
#pragma unroll
    for (int n = 0; n < 4; ++n) {
      const bf8 k0 = *(const bf8*)(Klb + kla0 + n * 2048);
      const bf8 k1 = *(const bf8*)(Klb + kla1 + n * 2048);
      accS[n] = __builtin_amdgcn_mfma_f32_16x16x32_bf16(k0, q0, accS[n], 0, 0, 0);
      accS[n] = __builtin_amdgcn_mfma_f32_16x16x32_bf16(k1, q1, accS[n], 0, 0, 0);
    }
    __builtin_amdgcn_s_setprio(0);

    // p = exp(sv*0.125 - 12) (fixed-max softmax); diag applies causal mask
    bf4 pa[4];
#pragma unroll
    for (int n = 0; n < 4; ++n) {
      float p[4];
#pragma unroll
      for (int reg = 0; reg < 4; ++reg) {
        float pv = __expf(fmaf(accS[n][reg], 0.125f, -12.0f));
        if constexpr (DIAG) {
          const bool ok = (n * 16 + hi * 4 + reg) <= (w * 16 + lr);
          pv = ok ? pv : 0.f;
        }
        p[reg] = pv;
        lsum4[reg] += pv;
      }
      union { int2 i; bf4 v; } u;
      u.i.x = (int)cvt_pk_bf16(p[0], p[1]);
      u.i.y = (int)cvt_pk_bf16(p[2], p[3]);
      pa[n] = u.v;
    }

    // PV: O[q][e] += P16[np] @ V16[np], A from registers, B b64 from LDS
    __builtin_amdgcn_s_setprio(1);
#pragma unroll
    for (int np = 0; np < 4; ++np) {
#pragma unroll
      for (int ne = 0; ne < 4; ++ne) {
        const bf4 vf = *(const bf4*)(Vlb + vla[np] + ne * 2048);
        accO[ne] = __builtin_amdgcn_mfma_f32_16x16x16bf16_1k(pa[np], vf, accO[ne], 0, 0, 0);
      }
    }
    __builtin_amdgcn_s_setprio(0);
  };

  auto epi = [&](int qt) {
    float lv = (lsum4[0] + lsum4[1]) + (lsum4[2] + lsum4[3]);
    lv += __shfl_xor(lv, 16);
    lv += __shfl_xor(lv, 32);   // all lanes: full denominator for q = lr
#pragma unroll
    for (int reg = 0; reg < 4; ++reg) {
      const float lq = __shfl(lv, hi * 4 + reg);
      const float inv = 1.f / lq;
      const int s = qt * 64 + w * 16 + hi * 4 + reg;
      short* op = PVb + (size_t)(b * S + s) * (H * D) + h * D;
#pragma unroll
      for (int n = 0; n < 4; ++n) op[n * 16 + lr] = f2bf(accO[n][reg] * inv);
    }
  };

  auto issue_chunk = [&](int c) {
    const int kt = (c < nA) ? c : c - nA;
    const size_t ko = (size_t)kt << 12;  // shorts: kt*64 rows * 64
    const size_t vo = (size_t)kt << 6;   // shorts: kt*64 cols
    const int bb = c & 3;
    gload16(kg0 + ko, &Ks[bb][tid * 8]);
    gload16(kg1 + ko, &Ks[bb][(256 + tid) * 8]);
    gload16(vg0 + vo, &Vs[bb][tid * 8]);
    gload16(vg1 + vo, &Vs[bb][(256 + tid) * 8]);
  };

  auto do_chunk = [&](int c) {
    const int bb = c & 3;
    if (c < nA) {
      if (c == nA - 1) {
        step(bb, qA0, qA1, std::true_type{});
        epi(qtA);                       // phase A done: write + reset
#pragma unroll
        for (int n = 0; n < 4; ++n) accO[n] = f4{0.f, 0.f, 0.f, 0.f};
        lsum4[0] = lsum4[1] = lsum4[2] = lsum4[3] = 0.f;
      } else {
        step(bb, qA0, qA1, std::false_type{});
      }
    } else {
      if (c == 32) step(bb, qB0, qB1, std::true_type{});
      else         step(bb, qB0, qB1, std::false_type{});
    }
  };

  // prologue: issue chunks 0 and 1
  issue_chunk(0);
  issue_chunk(1);

  for (int s = 0; s < 17; ++s) {
    if (s > 0) {
      __builtin_amdgcn_s_barrier();   // prior super-step's reads complete
      __builtin_amdgcn_sched_barrier(0);
    }
    const int c0 = 2 * s, c1 = c0 + 1;
    const int p0 = c0 + 2, p1 = c0 + 3;
    if (p0 < 33) issue_chunk(p0);
    if (p1 < 33) issue_chunk(p1);
    if (p1 < 33) {
      asm volatile("s_waitcnt vmcnt(8)" ::: "memory");
    } else if (p0 < 33) {
      asm volatile("s_waitcnt vmcnt(4)" ::: "memory");
    } else {
      asm volatile("s_waitcnt vmcnt(0)" ::: "memory");
    }
    __builtin_amdgcn_sched_barrier(0);
    __builtin_amdgcn_s_barrier();     // current chunks' loads visible
    __builtin_amdgcn_sched_barrier(0);

    do_chunk(c0);
    if (c1 < 33) do_chunk(c1);
  }
  epi(qtB);
}

}  // namespace

extern "C" void kernel_launch(void* const* d_in, const int* in_sizes, int n_in,
                              void* d_out, int out_size, void* d_ws, size_t ws_size,
                              hipStream_t stream) {
  const float* x   = (const float*)d_in[0];
  const float* Wq  = (const float*)d_in[1];
  const float* Wk  = (const float*)d_in[2];
  const float* Wvd = (const float*)d_in[3];
  const float* Wvu = (const float*)d_in[4];
  const float* Wo  = (const float*)d_in[5];
  float* out = (float*)d_out;

  const size_t nqk = (size_t)B * H * S * D;  // 4.19M
  short* xb    = (short*)d_ws;
  short* Qb    = xb + nqk;
  short* Kb    = Qb + nqk;
  short* Vtg   = Kb + nqk;
  short* PVb   = Vtg + nqk;
  short* WcatT = PVb + nqk;            // [1536][512]
  short* W2T   = WcatT + 1536 * KD;    // [512][512]

  prep_kernel<<<dim3(2304), 256, 0, stream>>>(x, Wq, Wk, Wvd, Wvu, Wo,
                                              xb, WcatT, W2T);
  gemm_kernel<0><<<dim3(64, 12), 256, 0, stream>>>(xb, WcatT, Qb, Kb, Vtg, nullptr);
  attn_kernel<<<dim3(B * H, 16), 256, 0, stream>>>(Qb, Kb, Vtg, PVb);
  gemm_kernel<1><<<dim3(64, 4), 256, 0, stream>>>(PVb, W2T, nullptr, nullptr, nullptr, out);
}

// Round 13
// 75.155 us; speedup vs baseline: 1.1691x; 1.1042x over previous
//
#include <hip/hip_runtime.h>
#include <math.h>
#include <type_traits>

namespace {
constexpr int B = 4, S = 2048, E = 512, D = 64, H = 8;
constexpr int KD = 512;

typedef short bf8 __attribute__((ext_vector_type(8)));
typedef short bf4 __attribute__((ext_vector_type(4)));
typedef float f4 __attribute__((ext_vector_type(4)));

__device__ __forceinline__ short f2bf(float f) {
  union { float f; unsigned u; } v; v.f = f;
  const unsigned r = v.u + 0x7fffu + ((v.u >> 16) & 1u);  // RNE
  return (short)(r >> 16);
}

__device__ __forceinline__ unsigned cvt_pk_bf16(float a, float b) {
  unsigned r;
  asm("v_cvt_pk_bf16_f32 %0, %1, %2" : "=v"(r) : "v"(a), "v"(b));
  return r;  // lo16 = bf16(a), hi16 = bf16(b)
}

__device__ __forceinline__ void gload16(const void* g, void* l) {
  __builtin_amdgcn_global_load_lds(
      (const __attribute__((address_space(1))) unsigned int*)g,
      (__attribute__((address_space(3))) unsigned int*)l, 16, 0, 0);
}

// ---------------------------------------------------------------------------
// fused prep: [0,2048) xb convert; [2048,2240) WcatT; [2240,2304) W2T
// Wq panels (cb<8) are prescaled by exact 0.125 (softmax scale, pow-2).
// ---------------------------------------------------------------------------
__global__ __launch_bounds__(256) void prep_kernel(
    const float* __restrict__ x, const float* __restrict__ Wq,
    const float* __restrict__ Wk, const float* __restrict__ Wvd,
    const float* __restrict__ Wvu, const float* __restrict__ Wo,
    short* __restrict__ xb, short* __restrict__ WcatT,
    short* __restrict__ W2T) {
  __shared__ float T[64][65];
  const int bid = blockIdx.x;
  const int tid = threadIdx.x;
  if (bid < 2048) {
    const size_t i = ((size_t)bid * 256 + tid) * 8;
    const float4 v0 = *(const float4*)(x + i);
    const float4 v1 = *(const float4*)(x + i + 4);
    bf8 o;
    o[0] = f2bf(v0.x); o[1] = f2bf(v0.y); o[2] = f2bf(v0.z); o[3] = f2bf(v0.w);
    o[4] = f2bf(v1.x); o[5] = f2bf(v1.y); o[6] = f2bf(v1.z); o[7] = f2bf(v1.w);
    *(bf8*)(xb + i) = o;
  } else if (bid < 2240) {
    const int r = bid - 2048;
    const int cb = r >> 3, e0 = (r & 7) * 64;
    const int w = cb >> 3, h = cb & 7;
    const float* Wsel = (w == 0) ? Wq : (w == 1) ? Wk : Wvd;
    const float* Wp = Wsel + (size_t)h * E * D;
    const float qs = (cb < 8) ? 0.125f : 1.0f;  // fold softmax scale into Wq
#pragma unroll
    for (int i = 0; i < 4; ++i) {
      const int f = tid + i * 256;
      const int rr = f >> 4, c4 = f & 15;
      const float4 v = *(const float4*)(Wp + (size_t)(e0 + rr) * D + c4 * 4);
      T[rr][c4 * 4 + 0] = v.x; T[rr][c4 * 4 + 1] = v.y;
      T[rr][c4 * 4 + 2] = v.z; T[rr][c4 * 4 + 3] = v.w;
    }
    __syncthreads();
#pragma unroll
    for (int i = 0; i < 4; ++i) {
      const int f = tid + i * 256;
      const int dr = f >> 4, e4 = f & 15;
      bf4 o;
#pragma unroll
      for (int j = 0; j < 4; ++j) o[j] = f2bf(T[e4 * 4 + j][dr] * qs);
      *(bf4*)(WcatT + (size_t)(cb * 64 + dr) * KD + e0 + e4 * 4) = o;
    }
  } else {
    const int r = bid - 2240;
    const int h = r >> 3, e0 = (r & 7) * 64;
    const float wo = Wo[h];
#pragma unroll
    for (int i = 0; i < 4; ++i) {
      const int f = tid + i * 256;
      const int rr = f >> 4, c4 = f & 15;
      const float4 v = *(const float4*)(Wvu + ((size_t)h * D + rr) * E + e0 + c4 * 4);
      T[rr][c4 * 4 + 0] = v.x * wo; T[rr][c4 * 4 + 1] = v.y * wo;
      T[rr][c4 * 4 + 2] = v.z * wo; T[rr][c4 * 4 + 3] = v.w * wo;
    }
    __syncthreads();
#pragma unroll
    for (int i = 0; i < 4; ++i) {
      const int f = tid + i * 256;
      const int er = f >> 4, d4 = f & 15;
      bf4 o;
#pragma unroll
      for (int j = 0; j < 4; ++j) o[j] = f2bf(T[d4 * 4 + j][er]);
      *(bf4*)(W2T + (size_t)(e0 + er) * KD + h * 64 + d4 * 4) = o;
    }
  }
}

// ---------------------------------------------------------------------------
// bf16 MFMA GEMM.  MODE 0: proj -> Qb/Kb (row-major [bh][s][d]) and V^T
// (Vt[bh][d][s], bf4 stores; 8B halves of each 16B granule swapped for rows
// with (d>>3)&1 -- bank-spread permutation consumed by attn).
// MODE 1: out epilogue (fp32 row-major).
// ---------------------------------------------------------------------------
template <int MODE>
__global__ __launch_bounds__(256) void gemm_kernel(
    const short* __restrict__ A, const short* __restrict__ Bt,
    short* __restrict__ Qb, short* __restrict__ Kb, short* __restrict__ Vtg,
    float* __restrict__ Of) {
  const int row0 = blockIdx.x * 128;
  const int ct = blockIdx.y;
  const int tid = threadIdx.x;
  const int w = tid >> 6, l = tid & 63;
  const int wm = w >> 1, wn = w & 1;
  const int lr = l & 15, hi = l >> 4;

  __shared__ short As[128 * 64];
  __shared__ short Bs[128 * 64];

  const short* Ag = A + (size_t)row0 * KD;
  const short* Bg = Bt + (size_t)ct * 128 * KD;

  f4 acc[4][4] = {};
  for (int k0 = 0; k0 < KD; k0 += 64) {
    __syncthreads();
#pragma unroll
    for (int i = 0; i < 4; ++i) {
      const int f = i * 256 + tid;
      const int r = f >> 3, g = f & 7;
      gload16(Ag + (size_t)r * KD + k0 + ((g ^ (r & 7)) << 3), &As[f * 8]);
    }
#pragma unroll
    for (int i = 0; i < 4; ++i) {
      const int f = i * 256 + tid;
      const int r = f >> 3, g = f & 7;
      gload16(Bg + (size_t)r * KD + k0 + ((g ^ (r & 7)) << 3), &Bs[f * 8]);
    }
    __syncthreads();

    bf8 af[4][2], bfv[4][2];
#pragma unroll
    for (int t = 0; t < 4; ++t) {
#pragma unroll
      for (int kh = 0; kh < 2; ++kh) {
        const int ar = wm * 64 + t * 16 + lr;
        af[t][kh] = *(const bf8*)&As[ar * 64 + (((kh * 4 + hi) ^ (ar & 7)) << 3)];
        const int br = wn * 64 + t * 16 + lr;
        bfv[t][kh] = *(const bf8*)&Bs[br * 64 + (((kh * 4 + hi) ^ (br & 7)) << 3)];
      }
    }
#pragma unroll
    for (int mt = 0; mt < 4; ++mt)
#pragma unroll
      for (int nt = 0; nt < 4; ++nt) {
        acc[mt][nt] =
            __builtin_amdgcn_mfma_f32_16x16x32_bf16(af[mt][0], bfv[nt][0], acc[mt][nt], 0, 0, 0);
        acc[mt][nt] =
            __builtin_amdgcn_mfma_f32_16x16x32_bf16(af[mt][1], bfv[nt][1], acc[mt][nt], 0, 0, 0);
      }
  }

  if constexpr (MODE == 0) {
#pragma unroll
    for (int nt = 0; nt < 4; ++nt) {
      const int gc = ct * 128 + wn * 64 + nt * 16 + lr;
      const int cb = gc >> 6, d = gc & 63;
      const int h = cb & 7;
      if (cb < 16) {
        short* Out = (cb < 8) ? Qb : Kb;
#pragma unroll
        for (int mt = 0; mt < 4; ++mt)
#pragma unroll
          for (int reg = 0; reg < 4; ++reg) {
            const int grow = row0 + wm * 64 + mt * 16 + hi * 4 + reg;
            const int b = grow >> 11, s = grow & (S - 1);
            Out[(((size_t)(b * H + h) * S + s) << 6) + d] = f2bf(acc[mt][nt][reg]);
          }
      } else {
        // V^T: Vt[bh][d][s]; swap 8B halves within 16B granules on rows
        // with (d>>3)&1 to spread LDS banks for attn's b64 reads.
        const int hswap = ((d >> 3) & 1) << 2;
#pragma unroll
        for (int mt = 0; mt < 4; ++mt) {
          const int grow0 = row0 + wm * 64 + mt * 16 + hi * 4;
          const int b = grow0 >> 11, s0 = (grow0 & (S - 1)) ^ hswap;
          bf4 o;
#pragma unroll
          for (int reg = 0; reg < 4; ++reg) o[reg] = f2bf(acc[mt][nt][reg]);
          *(bf4*)(Vtg + (((size_t)(b * H + h) * D + d) << 11) + s0) = o;
        }
      }
    }
  } else {
#pragma unroll
    for (int mt = 0; mt < 4; ++mt)
#pragma unroll
      for (int reg = 0; reg < 4; ++reg) {
        const int grow = row0 + wm * 64 + mt * 16 + hi * 4 + reg;
        float* orow = Of + (size_t)grow * 512 + ct * 128 + wn * 64;
#pragma unroll
        for (int nt = 0; nt < 4; ++nt) orow[nt * 16 + lr] = acc[mt][nt][reg];
      }
  }
}

// ---------------------------------------------------------------------------
// attn v10: split-T 8-wave blocks. Block (bh,j): qtA=j (nA=j+1 chunks),
// qtB=31-j (nB=32-j). 17 super-steps; stage 128 K-rows/V-cols per step;
// wave-group g2 computes chunk 2s+g2 of the current phase. Fixed-max softmax
// (scale pre-folded into Wq; p=__expf(sv), no offset -- cancels in normalize)
// makes partials linear: groups combine via LDS at the end.
// Pipeline shell = r8/r10 proven: dbuf, issue-then-vmcnt(4), 2 barriers.
// ---------------------------------------------------------------------------
__global__ __launch_bounds__(512, 4) void attn_kernel(
    const short* __restrict__ Qb, const short* __restrict__ Kb,
    const short* __restrict__ Vt, short* __restrict__ PVb) {
  const int bh = blockIdx.x;
  const int j = blockIdx.y;            // pair index 0..15
  const int qtA = j, qtB = 31 - j;
  const int nA = j + 1, nB = 32 - j;
  const int sA = (nA + 1) >> 1;        // A super-steps; total always 17
  const int b = bh >> 3, h = bh & 7;
  const int tid = threadIdx.x;
  const int w = tid >> 6, l = tid & 63;
  const int wl = w & 3, g2 = w >> 2;
  const int lr = l & 15, hi = l >> 4;

  __shared__ short Ks[2][128 * 64];    // 128 K-rows (2 chunks), dbuf
  __shared__ short Vs[2][128 * 64];    // 2x 64-col V sub-chunks, dbuf

  // Q fragments for both phases (B operand of swapped QK^T)
  const short* QgA = Qb + ((size_t)bh * S + qtA * 64 + wl * 16 + lr) * D;
  const short* QgB = Qb + ((size_t)bh * S + qtB * 64 + wl * 16 + lr) * D;
  const bf8 qA0 = *(const bf8*)(QgA + hi * 8);
  const bf8 qA1 = *(const bf8*)(QgA + 32 + hi * 8);
  const bf8 qB0 = *(const bf8*)(QgB + hi * 8);
  const bf8 qB1 = *(const bf8*)(QgB + 32 + hi * 8);

  const short* Kg = Kb + (size_t)bh * S * D;   // [t][64]
  const short* Vg = Vt + (size_t)bh * D * S;   // [e][S] (half-swapped)

  // staging lane addresses: 512 threads cover 128 rows x 8 granules
  const int sr = tid >> 3, sg = tid & 7;       // sr in [0,64)
  const int sswz = (sg ^ (sr & 7)) << 3;
  const short* kg0 = Kg + (size_t)sr * D + sswz;         // rows sr
  const short* kg1 = Kg + (size_t)(sr + 64) * D + sswz;  // rows sr+64 (same swz)
  const short* vg0 = Vg + (size_t)sr * S + sswz;         // e=sr, sub-chunk 0
  // sub-chunk 1 = vg0 + 64 cols

  // lane-constant LDS byte offsets (within a 64-row sub-chunk)
  const int e7 = lr & 7;
  const int kla0 = lr * 128 + ((hi ^ e7) << 4);
  const int kla1 = kla0 ^ 64;
  const int x7 = (hi >> 1) ^ e7;
  const int swaph = ((hi & 1) ^ ((lr >> 3) & 1)) << 3;
  int vla[4];
#pragma unroll
  for (int np = 0; np < 4; ++np)
    vla[np] = lr * 128 + (((2 * np) ^ x7) << 4) + swaph;
  const int gofs = g2 * 8192;          // group's sub-chunk base (bytes)

  float lsA[4] = {}, lsB[4] = {};
  f4 accA[4] = {}, accB[4] = {};

  auto stage = [&](int snext, int bb) {
    const int kt0 = (snext < sA) ? 2 * snext : 2 * (snext - sA);
    const size_t ko = (size_t)kt0 << 12;   // kt0*64 rows * 64 shorts
    const size_t vo = (size_t)kt0 << 6;    // kt0*64 cols
    gload16(kg0 + ko, &Ks[bb][tid * 8]);
    gload16(kg1 + ko, &Ks[bb][(512 + tid) * 8]);
    gload16(vg0 + vo, &Vs[bb][tid * 8]);
    gload16(vg0 + vo + 64, &Vs[bb][(512 + tid) * 8]);
  };

  auto step = [&](int bb, bf8 q0, bf8 q1, f4* aO, float* ls, auto diag_c) {
    constexpr bool DIAG = decltype(diag_c)::value;
    const char* Klb = (const char*)Ks[bb] + gofs;
    const char* Vlb = (const char*)Vs[bb] + gofs;
    f4 accS[4] = {};
    __builtin_amdgcn_s_setprio(1);
#pragma unroll
    for (int n = 0; n < 4; ++n) {
      const bf8 k0 = *(const bf8*)(Klb + kla0 + n * 2048);
      const bf8 k1 = *(const bf8*)(Klb + kla1 + n * 2048);
      accS[n] = __builtin_amdgcn_mfma_f32_16x16x32_bf16(k0, q0, accS[n], 0, 0, 0);
      accS[n] = __builtin_amdgcn_mfma_f32_16x16x32_bf16(k1, q1, accS[n], 0, 0, 0);
    }
    __builtin_amdgcn_s_setprio(0);

    // p = exp(sv) (scale folded into Wq; max-offset cancels in normalize)
    bf4 pa[4];
#pragma unroll
    for (int n = 0; n < 4; ++n) {
      float p[4];
#pragma unroll
      for (int reg = 0; reg < 4; ++reg) {
        float pv = __expf(accS[n][reg]);
        if constexpr (DIAG) {
          const bool ok = (n * 16 + hi * 4 + reg) <= (wl * 16 + lr);
          pv = ok ? pv : 0.f;
        }
        p[reg] = pv;
        ls[reg] += pv;
      }
      union { int2 i; bf4 v; } u;
      u.i.x = (int)cvt_pk_bf16(p[0], p[1]);
      u.i.y = (int)cvt_pk_bf16(p[2], p[3]);
      pa[n] = u.v;
    }

    __builtin_amdgcn_s_setprio(1);
#pragma unroll
    for (int np = 0; np < 4; ++np) {
#pragma unroll
      for (int ne = 0; ne < 4; ++ne) {
        const bf4 vf = *(const bf4*)(Vlb + vla[np] + ne * 2048);
        aO[ne] = __builtin_amdgcn_mfma_f32_16x16x16bf16_1k(pa[np], vf, aO[ne], 0, 0, 0);
      }
    }
    __builtin_amdgcn_s_setprio(0);
  };

  auto epi = [&](int qt, f4* aO, float* ls) {
    float lv = (ls[0] + ls[1]) + (ls[2] + ls[3]);
    lv += __shfl_xor(lv, 16);
    lv += __shfl_xor(lv, 32);   // full denominator for q = lr
#pragma unroll
    for (int reg = 0; reg < 4; ++reg) {
      const float lq = __shfl(lv, hi * 4 + reg);
      const float inv = 1.f / lq;
      const int s = qt * 64 + wl * 16 + hi * 4 + reg;
      short* op = PVb + (size_t)(b * S + s) * (H * D) + h * D;
#pragma unroll
      for (int n = 0; n < 4; ++n) op[n * 16 + lr] = f2bf(aO[n][reg] * inv);
    }
  };

  // prologue: stage super-step 0
  stage(0, 0);

  for (int s = 0; s < 17; ++s) {
    if (s > 0) {
      __builtin_amdgcn_s_barrier();   // prior super-step's reads complete
      __builtin_amdgcn_sched_barrier(0);
    }
    if (s < 16) {
      stage(s + 1, (s + 1) & 1);
      asm volatile("s_waitcnt vmcnt(4)" ::: "memory");  // this step's loads done
    } else {
      asm volatile("s_waitcnt vmcnt(0)" ::: "memory");
    }
    __builtin_amdgcn_sched_barrier(0);
    __builtin_amdgcn_s_barrier();
    __builtin_amdgcn_sched_barrier(0);

    const int bb = s & 1;
    if (s < sA) {
      const int c = 2 * s + g2;
      if (c < nA) {
        if (c == nA - 1) step(bb, qA0, qA1, accA, lsA, std::true_type{});
        else             step(bb, qA0, qA1, accA, lsA, std::false_type{});
      }
    } else {
      const int c = 2 * (s - sA) + g2;
      if (c < nB) {
        if (c == nB - 1) step(bb, qB0, qB1, accB, lsB, std::true_type{});
        else             step(bb, qB0, qB1, accB, lsB, std::false_type{});
      }
    }
  }

  // cross-group combine (fixed-max partials are linear), then epilogues
  __syncthreads();                     // all compute done; LDS free
  float* cbA = (float*)&Ks[0][0];      // 20KB used of 32KB
  float* cbB = (float*)&Vs[0][0];
  const int slot = (wl * 64 + l) * 20;
  if (g2 == 1) {
#pragma unroll
    for (int n = 0; n < 4; ++n)
#pragma unroll
      for (int reg = 0; reg < 4; ++reg) cbA[slot + n * 4 + reg] = accA[n][reg];
#pragma unroll
    for (int reg = 0; reg < 4; ++reg) cbA[slot + 16 + reg] = lsA[reg];
  } else {
#pragma unroll
    for (int n = 0; n < 4; ++n)
#pragma unroll
      for (int reg = 0; reg < 4; ++reg) cbB[slot + n * 4 + reg] = accB[n][reg];
#pragma unroll
    for (int reg = 0; reg < 4; ++reg) cbB[slot + 16 + reg] = lsB[reg];
  }
  __syncthreads();
  if (g2 == 0) {
#pragma unroll
    for (int n = 0; n < 4; ++n)
#pragma unroll
      for (int reg = 0; reg < 4; ++reg) accA[n][reg] += cbA[slot + n * 4 + reg];
#pragma unroll
    for (int reg = 0; reg < 4; ++reg) lsA[reg] += cbA[slot + 16 + reg];
    epi(qtA, accA, lsA);
  } else {
#pragma unroll
    for (int n = 0; n < 4; ++n)
#pragma unroll
      for (int reg = 0; reg < 4; ++reg) accB[n][reg] += cbB[slot + n * 4 + reg];
#pragma unroll
    for (int reg = 0; reg < 4; ++reg) lsB[reg] += cbB[slot + 16 + reg];
    epi(qtB, accB, lsB);
  }
}

}  // namespace

extern "C" void kernel_launch(void* const* d_in, const int* in_sizes, int n_in,
                              void* d_out, int out_size, void* d_ws, size_t ws_size,
                              hipStream_t stream) {
  const float* x   = (const float*)d_in[0];
  const float* Wq  = (const float*)d_in[1];
  const float* Wk  = (const float*)d_in[2];
  const float* Wvd = (const float*)d_in[3];
  const float* Wvu = (const float*)d_in[4];
  const float* Wo  = (const float*)d_in[5];
  float* out = (float*)d_out;

  const size_t nqk = (size_t)B * H * S * D;  // 4.19M
  short* xb    = (short*)d_ws;
  short* Qb    = xb + nqk;
  short* Kb    = Qb + nqk;
  short* Vtg   = Kb + nqk;
  short* PVb   = Vtg + nqk;
  short* WcatT = PVb + nqk;            // [1536][512]
  short* W2T   = WcatT + 1536 * KD;    // [512][512]

  prep_kernel<<<dim3(2304), 256, 0, stream>>>(x, Wq, Wk, Wvd, Wvu, Wo,
                                              xb, WcatT, W2T);
  gemm_kernel<0><<<dim3(64, 12), 256, 0, stream>>>(xb, WcatT, Qb, Kb, Vtg, nullptr);
  attn_kernel<<<dim3(B * H, 16), 512, 0, stream>>>(Qb, Kb, Vtg, PVb);
  gemm_kernel<1><<<dim3(64, 4), 256, 0, stream>>>(PVb, W2T, nullptr, nullptr, nullptr, out);
}